// Round 2
// baseline (193.844 us; speedup 1.0000x reference)
//
#include <hip/hip_runtime.h>
#include <math.h>

#define NROWS 32768
#define NDIM 64
#define NCODE 1024
#define AMB_CAP 8192
#define GAP_THRESH 6e-4f   // quantized-key granularity <=1.2e-4; split-bf16 noise ~2e-6

typedef __attribute__((ext_vector_type(8))) short bf16x8;   // 8 bf16 = 4 VGPRs
typedef __attribute__((ext_vector_type(4))) float f32x4;    // MFMA acc

__device__ __forceinline__ unsigned short bf16_rne(float f) {
    unsigned u = __float_as_uint(f);
    unsigned r = u + 0x7FFFu + ((u >> 16) & 1u);
    return (unsigned short)(r >> 16);
}

// ---------------------------------------------------------------------------
// prep: cnorm+4, minK init, counter/gsumsq zero, codebook -> frag-major
// split-bf16 (wsB). Layout: chunk cc=c>>6 (16KB) | tile ct=(c>>4)&3 (4KB) |
// frag q in {hi0,hi1,lo0,lo1} (1KB) | lane part L=g*16+(c&15): 16B = 8 bf16
// of dims (q&1)*32 + g*8 .. +8  (hi if q<2 else lo).
// ---------------------------------------------------------------------------
__global__ __launch_bounds__(256) void vq_prep(
    const float* __restrict__ cb, float* __restrict__ cn4,
    unsigned* __restrict__ minK, unsigned* __restrict__ counter,
    float* __restrict__ gsumsq, unsigned short* __restrict__ wsB)
{
    int c = blockIdx.x * 256 + threadIdx.x;
    if (c == 0) { *counter = 0u; *gsumsq = 0.f; }
    if (c >= NCODE) return;
    float v[64];
    const float4* src = (const float4*)(cb + (size_t)c * 64);
    float s = 0.f;
    #pragma unroll
    for (int i = 0; i < 16; i++) {
        float4 t = src[i];
        v[i*4+0] = t.x; v[i*4+1] = t.y; v[i*4+2] = t.z; v[i*4+3] = t.w;
        s += t.x*t.x + t.y*t.y + t.z*t.z + t.w*t.w;
    }
    cn4[c] = s + 4.0f;
    minK[c] = 0xFF800000u;  // okey(+inf)
    int cc = c >> 6, ct = (c >> 4) & 3, cl = c & 15;
    #pragma unroll
    for (int q = 0; q < 4; q++) {
        int half = q & 1, lo = q >> 1;
        #pragma unroll
        for (int g = 0; g < 4; g++) {
            unsigned short u8[8] __attribute__((aligned(16)));
            #pragma unroll
            for (int j = 0; j < 8; j++) {
                float f = v[half*32 + g*8 + j];
                unsigned short h = bf16_rne(f);
                if (lo) h = bf16_rne(f - __uint_as_float((unsigned)h << 16));
                u8[j] = h;
            }
            size_t off = (size_t)cc * 8192 + ct * 2048 + q * 512 + (g * 16 + cl) * 8; // ushort units
            *(uint4*)(wsB + off) = *(const uint4*)u8;
        }
    }
}

// ---------------------------------------------------------------------------
// main: block = 256 rows x 256-code quarter. 4 waves x 64 rows. A in regs
// (split-bf16 frags), B chunk (64 codes, 16KB) double-buffered in LDS.
// dist emulated via 6 MFMAs (hi*hi x2, hi*lo x2, lo*hi x2). Epilogue keys
// w=4+cn-2s quantized to 24 bits with 8-bit local code id packed in.
// Writes per-(row,quarter) top-2 keys into keysOut (=d_out scratch region).
// ---------------------------------------------------------------------------
__global__ __launch_bounds__(256, 2) void vq_main(
    const float* __restrict__ x, const unsigned short* __restrict__ wsB,
    const float* __restrict__ cn4, unsigned* __restrict__ minK,
    unsigned* __restrict__ keysOut)
{
    __shared__ __align__(16) unsigned char Bb[2][16384];

    const int tid = threadIdx.x;
    const int lane = tid & 63;
    const int w = tid >> 6;
    const int ln15 = lane & 15;
    const int q = lane >> 4;
    const int b = blockIdx.x;
    const int qtr = b & 3;
    const int row0 = (b >> 2) * 256 + w * 64;

    // ---- A: load 64 rows fp32 -> split-bf16 frags in regs; xn via shfl ----
    bf16x8 Ah0[4], Ah1[4], Al0[4], Al1[4];
    float xnm4[4][4];
    #pragma unroll
    for (int t = 0; t < 4; t++) {
        const float* xr = x + (size_t)(row0 + t*16 + ln15) * 64 + q * 8;
        float4 f0 = *(const float4*)xr;
        float4 f1 = *(const float4*)(xr + 4);
        float4 f2 = *(const float4*)(xr + 32);
        float4 f3 = *(const float4*)(xr + 36);
        float fa[8] = {f0.x,f0.y,f0.z,f0.w,f1.x,f1.y,f1.z,f1.w};
        float fb[8] = {f2.x,f2.y,f2.z,f2.w,f3.x,f3.y,f3.z,f3.w};
        unsigned short h[8]  __attribute__((aligned(16)));
        unsigned short l[8]  __attribute__((aligned(16)));
        unsigned short h2[8] __attribute__((aligned(16)));
        unsigned short l2[8] __attribute__((aligned(16)));
        float ss = 0.f;
        #pragma unroll
        for (int j = 0; j < 8; j++) {
            ss += fa[j]*fa[j] + fb[j]*fb[j];
            unsigned short hh = bf16_rne(fa[j]);
            h[j] = hh; l[j] = bf16_rne(fa[j] - __uint_as_float((unsigned)hh << 16));
            hh = bf16_rne(fb[j]);
            h2[j] = hh; l2[j] = bf16_rne(fb[j] - __uint_as_float((unsigned)hh << 16));
        }
        Ah0[t] = *(const bf16x8*)h;  Al0[t] = *(const bf16x8*)l;
        Ah1[t] = *(const bf16x8*)h2; Al1[t] = *(const bf16x8*)l2;
        ss += __shfl_xor(ss, 16);
        ss += __shfl_xor(ss, 32);   // full ||x||^2 of row row0+t*16+ln15, all lanes of that ln15
        #pragma unroll
        for (int r = 0; r < 4; r++)
            xnm4[t][r] = __shfl(ss, (q << 2) | r, 64) - 4.0f;  // xn of tile-row q*4+r
    }

    unsigned m1[4][4], m2[4][4];
    #pragma unroll
    for (int t = 0; t < 4; t++)
        #pragma unroll
        for (int r = 0; r < 4; r++) { m1[t][r] = 0xFFFFFFFFu; m2[t][r] = 0xFFFFFFFFu; }

    // ---- B chunk loop: 4 chunks x 64 codes, double-buffered LDS ----
    const float4* wsBq = (const float4*)(wsB + (size_t)qtr * 32768); // quarter = 4 chunks x 16KB
    float4 st[4];
    #pragma unroll
    for (int i = 0; i < 4; i++) st[i] = wsBq[i*256 + tid];
    #pragma unroll
    for (int i = 0; i < 4; i++) *(float4*)(Bb[0] + (i*256 + tid)*16) = st[i];

    for (int cc = 0; cc < 4; cc++) {
        __syncthreads();   // buf[cc&1] staged
        if (cc < 3) {
            #pragma unroll
            for (int i = 0; i < 4; i++) st[i] = wsBq[(cc+1)*1024 + i*256 + tid];
        }
        const unsigned char* buf = Bb[cc & 1];
        #pragma unroll
        for (int ct = 0; ct < 4; ct++) {
            bf16x8 Bh0 = *(const bf16x8*)(buf + ct*4096 +    0 + lane*16);
            bf16x8 Bh1 = *(const bf16x8*)(buf + ct*4096 + 1024 + lane*16);
            bf16x8 Bl0 = *(const bf16x8*)(buf + ct*4096 + 2048 + lane*16);
            bf16x8 Bl1 = *(const bf16x8*)(buf + ct*4096 + 3072 + lane*16);
            float cn4v = cn4[qtr*256 + cc*64 + ct*16 + ln15];
            unsigned korpat = 0x80000000u | (unsigned)(cc*64 + ct*16 + ln15);
            float cmin = INFINITY;
            #pragma unroll
            for (int t = 0; t < 4; t++) {
                f32x4 acc = {0.f, 0.f, 0.f, 0.f};
                acc = __builtin_amdgcn_mfma_f32_16x16x32_bf16(Ah0[t], Bh0, acc, 0, 0, 0);
                acc = __builtin_amdgcn_mfma_f32_16x16x32_bf16(Ah1[t], Bh1, acc, 0, 0, 0);
                acc = __builtin_amdgcn_mfma_f32_16x16x32_bf16(Ah0[t], Bl0, acc, 0, 0, 0);
                acc = __builtin_amdgcn_mfma_f32_16x16x32_bf16(Ah1[t], Bl1, acc, 0, 0, 0);
                acc = __builtin_amdgcn_mfma_f32_16x16x32_bf16(Al0[t], Bh0, acc, 0, 0, 0);
                acc = __builtin_amdgcn_mfma_f32_16x16x32_bf16(Al1[t], Bh1, acc, 0, 0, 0);
                #pragma unroll
                for (int r = 0; r < 4; r++) {
                    float wv = fmaf(acc[r], -2.0f, cn4v);           // 4 + cn - 2s  (>0)
                    unsigned kk = (__float_as_uint(wv) & 0xFFFFFF00u) | korpat;
                    unsigned mx = m1[t][r] > kk ? m1[t][r] : kk;
                    m2[t][r] = m2[t][r] < mx ? m2[t][r] : mx;
                    m1[t][r] = m1[t][r] < kk ? m1[t][r] : kk;
                    float de = wv + xnm4[t][r];                     // full dist (entropy)
                    cmin = fminf(cmin, de);
                }
            }
            cmin = fminf(cmin, __shfl_xor(cmin, 16));
            cmin = fminf(cmin, __shfl_xor(cmin, 32));
            if (lane < 16) {
                int kg = qtr*256 + cc*64 + ct*16 + lane;
                unsigned ky = __float_as_uint(cmin) | 0x80000000u;
                if (ky < minK[kg]) atomicMin(&minK[kg], ky);
            }
        }
        if (cc < 3) {
            #pragma unroll
            for (int i = 0; i < 4; i++) *(float4*)(Bb[(cc+1)&1] + (i*256 + tid)*16) = st[i];
        }
    }

    // ---- merge top-2 across the 16 lanes of each q-group ----
    #pragma unroll
    for (int d = 1; d < 16; d <<= 1) {
        #pragma unroll
        for (int t = 0; t < 4; t++)
            #pragma unroll
            for (int r = 0; r < 4; r++) {
                unsigned o1 = (unsigned)__shfl_xor((int)m1[t][r], d);
                unsigned o2 = (unsigned)__shfl_xor((int)m2[t][r], d);
                unsigned mx  = m1[t][r] > o1 ? m1[t][r] : o1;
                unsigned mn2 = m2[t][r] < o2 ? m2[t][r] : o2;
                m2[t][r] = mn2 < mx ? mn2 : mx;
                m1[t][r] = m1[t][r] < o1 ? m1[t][r] : o1;
            }
    }
    #pragma unroll
    for (int t = 0; t < 4; t++)
        #pragma unroll
        for (int r = 0; r < 4; r++)
            if (ln15 == t*4 + r) {
                int row = row0 + t*16 + q*4 + r;
                uint2 v2; v2.x = m1[t][r]; v2.y = m2[t][r];
                *(uint2*)(keysOut + (size_t)row*8 + qtr*2) = v2;
            }
}

// ---------------------------------------------------------------------------
// token: merge the 4 quarter top-2 keys per row -> token + ambiguity list
// ---------------------------------------------------------------------------
__global__ __launch_bounds__(256) void vq_token(
    const unsigned* __restrict__ keysOut, int* __restrict__ token,
    unsigned* __restrict__ counter, int* __restrict__ amb)
{
    int row = blockIdx.x * 256 + threadIdx.x;
    if (row >= NROWS) return;
    uint4 a = *(const uint4*)(keysOut + (size_t)row*8);
    uint4 b = *(const uint4*)(keysOut + (size_t)row*8 + 4);
    unsigned q1[4] = {a.x, a.z, b.x, b.z};
    unsigned q2[4] = {a.y, a.w, b.y, b.w};
    unsigned W1 = 0xFFFFFFFFu, W2 = 0xFFFFFFFFu; int K1 = 0;
    #pragma unroll
    for (int qq = 0; qq < 4; qq++) {
        unsigned v1 = q1[qq] & 0xFFFFFF00u;
        unsigned v2 = q2[qq] & 0xFFFFFF00u;
        int k1 = qq*256 + (int)(q1[qq] & 0xFFu);
        if (v1 < W1) { W2 = W1 < v2 ? W1 : v2; K1 = k1; W1 = v1; }
        else         { W2 = W2 < v1 ? W2 : v1; }
    }
    token[row] = K1;
    float gap = __uint_as_float(W2 ^ 0x80000000u) - __uint_as_float(W1 ^ 0x80000000u);
    if (gap < GAP_THRESH) {
        unsigned idx = atomicAdd(counter, 1u);
        if (idx < AMB_CAP) { amb[2*idx] = row; amb[2*idx+1] = K1; }
    }
}

// ---------------------------------------------------------------------------
// emb: gather chosen codes -> out, accumulate sum((emb-x)^2)
// ---------------------------------------------------------------------------
__global__ __launch_bounds__(256) void vq_emb(
    const float* __restrict__ x, const float* __restrict__ cb,
    const int* __restrict__ token, float* __restrict__ out,
    float* __restrict__ gsumsq)
{
    __shared__ float redS[4];
    int tid = threadIdx.x;
    int row = blockIdx.x * 64 + (tid >> 2);
    int p = tid & 3;
    int tok = token[row];
    const float4* cv = (const float4*)(cb + (size_t)tok*64 + p*16);
    const float4* xv = (const float4*)(x  + (size_t)row*64 + p*16);
    float4* ov = (float4*)(out + (size_t)row*64 + p*16);
    float acc = 0.f;
    #pragma unroll
    for (int i = 0; i < 4; i++) {
        float4 c = cv[i]; float4 xx = xv[i];
        ov[i] = c;
        float dx = c.x-xx.x, dy = c.y-xx.y, dz = c.z-xx.z, dw = c.w-xx.w;
        acc += dx*dx + dy*dy + dz*dz + dw*dw;
    }
    #pragma unroll
    for (int o = 32; o > 0; o >>= 1) acc += __shfl_down(acc, o);
    if ((tid & 63) == 0) redS[tid >> 6] = acc;
    __syncthreads();
    if (tid == 0) atomicAdd(gsumsq, redS[0] + redS[1] + redS[2] + redS[3]);
}

// ---------------------------------------------------------------------------
// fixup: block-per-ambiguous-row full fp64 argmin over all 1024 codes
// (code-parallel across threads; identical decisions to round-1 fp64 path)
// ---------------------------------------------------------------------------
__global__ __launch_bounds__(256) void vq_fixup(
    const float* __restrict__ x, const float* __restrict__ cb,
    float* __restrict__ out, const unsigned* __restrict__ counter,
    const int* __restrict__ amb, float* __restrict__ gsumsq)
{
    __shared__ double xs[64];
    __shared__ double bd[256];
    __shared__ int    bi[256];
    int tid = threadIdx.x;
    unsigned cnt = *counter; if (cnt > AMB_CAP) cnt = AMB_CAP;
    for (unsigned i = blockIdx.x; i < cnt; i += gridDim.x) {
        int row = amb[2*i], oldk = amb[2*i+1];
        __syncthreads();
        if (tid < 64) xs[tid] = (double)x[(size_t)row*64 + tid];
        __syncthreads();
        double xn = 0.0;
        for (int d = 0; d < 64; d++) xn += xs[d]*xs[d];
        double best = INFINITY; int bk = 1 << 30;
        for (int j = 0; j < 4; j++) {
            int k = tid + j*256;
            const float* cr = cb + (size_t)k*64;
            double dot = 0.0, cn2 = 0.0;
            for (int d = 0; d < 64; d++) {
                double cvd = (double)cr[d];
                dot += xs[d]*cvd; cn2 += cvd*cvd;
            }
            double dist = (xn - 2.0*dot) + cn2;
            if (dist < best || (dist == best && k < bk)) { best = dist; bk = k; }
        }
        bd[tid] = best; bi[tid] = bk;
        __syncthreads();
        for (int s = 128; s > 0; s >>= 1) {
            if (tid < s) {
                double od = bd[tid+s]; int ok = bi[tid+s];
                if (od < bd[tid] || (od == bd[tid] && ok < bi[tid])) { bd[tid] = od; bi[tid] = ok; }
            }
            __syncthreads();
        }
        int bestk = bi[0];
        if (bestk != oldk) {
            double part = 0.0;
            if (tid < 64) {
                float cn = cb[(size_t)bestk*64 + tid];
                float co = cb[(size_t)oldk*64 + tid];
                out[(size_t)row*64 + tid] = cn;
                double dn = (double)cn - xs[tid];
                double dl = (double)co - xs[tid];
                part = dn*dn - dl*dl;
            }
            __syncthreads();
            bd[tid] = part;
            __syncthreads();
            for (int s = 128; s > 0; s >>= 1) {
                if (tid < s) bd[tid] += bd[tid+s];
                __syncthreads();
            }
            if (tid == 0) atomicAdd(gsumsq, (float)bd[0]);
        }
    }
}

// ---------------------------------------------------------------------------
// finalize: loss = 1.25*sumsq/2097152 + 0.1*mean(per-code min dist)
// ---------------------------------------------------------------------------
__global__ __launch_bounds__(256) void vq_finalize(
    const unsigned* __restrict__ minK, const float* __restrict__ gsumsq,
    float* __restrict__ out_loss)
{
    __shared__ float redS[4];
    float s = 0.f;
    for (int k = threadIdx.x; k < NCODE; k += 256) {
        unsigned u = minK[k];
        unsigned b = (u & 0x80000000u) ? (u ^ 0x80000000u) : ~u;
        s += __uint_as_float(b);
    }
    #pragma unroll
    for (int o = 32; o > 0; o >>= 1) s += __shfl_down(s, o);
    if ((threadIdx.x & 63) == 0) redS[threadIdx.x >> 6] = s;
    __syncthreads();
    if (threadIdx.x == 0) {
        float tot = redS[0] + redS[1] + redS[2] + redS[3];
        out_loss[0] = 1.25f * (*gsumsq / 2097152.0f) + 0.1f * (tot / 1024.0f);
    }
}

extern "C" void kernel_launch(void* const* d_in, const int* in_sizes, int n_in,
                              void* d_out, int out_size, void* d_ws, size_t ws_size,
                              hipStream_t stream) {
    const float* x  = (const float*)d_in[0];   // [32768, 64]
    const float* cb = (const float*)d_in[1];   // [1024, 64]
    float* out = (float*)d_out;                // [0,2097152): emb; [2097152]: loss

    char* ws = (char*)d_ws;
    unsigned*       counter = (unsigned*)ws;                    // @0
    float*          gsumsq  = (float*)(ws + 4);                 // @4
    float*          cn4     = (float*)(ws + 256);               // 4 KB
    unsigned*       minK    = (unsigned*)(ws + 4352);           // 4 KB
    int*            token   = (int*)(ws + 8448);                // 128 KB
    int*            amb     = (int*)(ws + 139520);              // 64 KB
    unsigned short* wsB     = (unsigned short*)(ws + 205056);   // 256 KB frag-major split-bf16

    unsigned* keysOut = (unsigned*)d_out;  // 1 MB scratch inside out; overwritten by vq_emb

    vq_prep    <<<4,   256, 0, stream>>>(cb, cn4, minK, counter, gsumsq, wsB);
    vq_main    <<<512, 256, 0, stream>>>(x, wsB, cn4, minK, keysOut);
    vq_token   <<<128, 256, 0, stream>>>(keysOut, token, counter, amb);
    vq_emb     <<<512, 256, 0, stream>>>(x, cb, token, out, gsumsq);
    vq_fixup   <<<128, 256, 0, stream>>>(x, cb, out, counter, amb, gsumsq);
    vq_finalize<<<1,   256, 0, stream>>>(minK, gsumsq, out + 2097152);
}

// Round 3
// 157.194 us; speedup vs baseline: 1.2331x; 1.2331x over previous
//
#include <hip/hip_runtime.h>
#include <math.h>

#define NROWS 32768
#define NCODE 1024
#define AMB_CAP 8192
#define GAP_THRESH 2e-3f   // key quantization 4.9e-4 + split-bf16 noise ~2e-6

typedef __attribute__((ext_vector_type(8))) short bf16x8;   // 8 bf16 = 4 VGPRs
typedef __attribute__((ext_vector_type(4))) float f32x4;    // MFMA acc

__device__ __forceinline__ unsigned short bf16_rne(float f) {
    unsigned u = __float_as_uint(f);
    unsigned r = u + 0x7FFFu + ((u >> 16) & 1u);
    return (unsigned short)(r >> 16);
}

// ---------------------------------------------------------------------------
// prep: cn4 = ||c||^2+4, counter/gsumsq zero, codebook -> frag-major split-bf16.
// Layout: chunk cc=c>>6 (16KB) | tile ct=(c>>4)&3 (4KB) | frag q {hi0,hi1,lo0,lo1}
// (1KB) | lane (g*16 + c&15)*16B = 8 bf16 of dims (q&1)*32+g*8..+8.
// ---------------------------------------------------------------------------
__global__ __launch_bounds__(256) void vq_prep(
    const float* __restrict__ cb, float* __restrict__ cn4,
    unsigned* __restrict__ counter, float* __restrict__ gsumsq,
    unsigned short* __restrict__ wsB)
{
    int c = blockIdx.x * 256 + threadIdx.x;
    if (c == 0) { *counter = 0u; *gsumsq = 0.f; }
    if (c >= NCODE) return;
    float v[64];
    const float4* src = (const float4*)(cb + (size_t)c * 64);
    float s = 0.f;
    #pragma unroll
    for (int i = 0; i < 16; i++) {
        float4 t = src[i];
        v[i*4+0] = t.x; v[i*4+1] = t.y; v[i*4+2] = t.z; v[i*4+3] = t.w;
        s += t.x*t.x + t.y*t.y + t.z*t.z + t.w*t.w;
    }
    cn4[c] = s + 4.0f;
    int cc = c >> 6, ct = (c >> 4) & 3, cl = c & 15;
    #pragma unroll
    for (int q = 0; q < 4; q++) {
        int half = q & 1, lo = q >> 1;
        #pragma unroll
        for (int g = 0; g < 4; g++) {
            unsigned short u8[8] __attribute__((aligned(16)));
            #pragma unroll
            for (int j = 0; j < 8; j++) {
                float f = v[half*32 + g*8 + j];
                unsigned short h = bf16_rne(f);
                if (lo) h = bf16_rne(f - __uint_as_float((unsigned)h << 16));
                u8[j] = h;
            }
            size_t off = (size_t)cc * 8192 + ct * 2048 + q * 512 + (g * 16 + cl) * 8;
            *(uint4*)(wsB + off) = *(const uint4*)u8;
        }
    }
}

// ---------------------------------------------------------------------------
// main: block = 64 rows x ALL 1024 codes; 4 waves, wave wi owns rows wi*16..+16.
// B: 16 chunks x 64 codes, double-buffered LDS. 6 MFMAs emulate fp32 dot.
// Keys: w = 4+cn-2s, low 10 mantissa bits replaced by code id; top-2 in regs,
// butterfly-merged -> token + gap in-block. Entropy: per-chunk per-code wave
// min -> scrE LDS -> per-block entPartial (coalesced). Emb gather + sumsq fused.
// ---------------------------------------------------------------------------
__global__ __launch_bounds__(256, 2) void vq_main(
    const float* __restrict__ x, const float* __restrict__ cb,
    const unsigned short* __restrict__ wsB, const float* __restrict__ cn4,
    float* __restrict__ out, float* __restrict__ entPartial,
    unsigned* __restrict__ counter, int* __restrict__ amb,
    float* __restrict__ gsumsq)
{
    __shared__ __align__(16) unsigned char Bb[2][16384];
    __shared__ float scrE[4096];   // [wave][1024] per-code min over wave's rows
    __shared__ int   tokS[64];
    __shared__ float redS[4];

    const int tid = threadIdx.x;
    const int lane = tid & 63;
    const int wi = tid >> 6;
    const int ln15 = lane & 15;
    const int q = lane >> 4;
    const int row0 = blockIdx.x * 64;
    const int wrow = row0 + wi * 16;

    // ---- A: 16 rows fp32 -> split-bf16 frags in regs; row norms via shfl ----
    bf16x8 Ah0, Ah1, Al0, Al1;
    float xnm4[4];
    {
        const float* xr = x + (size_t)(wrow + ln15) * 64 + q * 8;
        float4 f0 = *(const float4*)xr;
        float4 f1 = *(const float4*)(xr + 4);
        float4 f2 = *(const float4*)(xr + 32);
        float4 f3 = *(const float4*)(xr + 36);
        float fa[8] = {f0.x,f0.y,f0.z,f0.w,f1.x,f1.y,f1.z,f1.w};
        float fb[8] = {f2.x,f2.y,f2.z,f2.w,f3.x,f3.y,f3.z,f3.w};
        unsigned short h[8]  __attribute__((aligned(16)));
        unsigned short l[8]  __attribute__((aligned(16)));
        unsigned short h2[8] __attribute__((aligned(16)));
        unsigned short l2[8] __attribute__((aligned(16)));
        float ss = 0.f;
        #pragma unroll
        for (int j = 0; j < 8; j++) {
            ss += fa[j]*fa[j] + fb[j]*fb[j];
            unsigned short hh = bf16_rne(fa[j]);
            h[j] = hh; l[j] = bf16_rne(fa[j] - __uint_as_float((unsigned)hh << 16));
            hh = bf16_rne(fb[j]);
            h2[j] = hh; l2[j] = bf16_rne(fb[j] - __uint_as_float((unsigned)hh << 16));
        }
        Ah0 = *(const bf16x8*)h;  Al0 = *(const bf16x8*)l;
        Ah1 = *(const bf16x8*)h2; Al1 = *(const bf16x8*)l2;
        ss += __shfl_xor(ss, 16);
        ss += __shfl_xor(ss, 32);            // ||x_row(ln15)||^2
        #pragma unroll
        for (int r = 0; r < 4; r++)
            xnm4[r] = __shfl(ss, (q << 2) | r, 64) - 4.0f;  // xn(row q*4+r) - 4
    }

    unsigned m1[4], m2[4];
    #pragma unroll
    for (int r = 0; r < 4; r++) { m1[r] = 0xFFFFFFFFu; m2[r] = 0xFFFFFFFFu; }

    // ---- chunk loop over all 1024 codes, double-buffered staging ----
    const float4* wsB4 = (const float4*)wsB;   // chunk = 1024 float4 (16 KB)
    float4 st[4];
    #pragma unroll
    for (int i = 0; i < 4; i++) st[i] = wsB4[i*256 + tid];
    #pragma unroll
    for (int i = 0; i < 4; i++) *(float4*)(Bb[0] + (i*256 + tid)*16) = st[i];

    for (int cc = 0; cc < 16; cc++) {
        __syncthreads();   // buf[cc&1] staged; prev chunk fully consumed
        if (cc < 15) {
            #pragma unroll
            for (int i = 0; i < 4; i++) st[i] = wsB4[(cc+1)*1024 + i*256 + tid];
        }
        const unsigned char* buf = Bb[cc & 1];
        #pragma unroll
        for (int ct = 0; ct < 4; ct++) {
            bf16x8 Bh0 = *(const bf16x8*)(buf + ct*4096 +    0 + lane*16);
            bf16x8 Bh1 = *(const bf16x8*)(buf + ct*4096 + 1024 + lane*16);
            bf16x8 Bl0 = *(const bf16x8*)(buf + ct*4096 + 2048 + lane*16);
            bf16x8 Bl1 = *(const bf16x8*)(buf + ct*4096 + 3072 + lane*16);
            float cn4v = cn4[cc*64 + ct*16 + ln15];
            unsigned kid = (unsigned)(cc*64 + ct*16 + ln15);
            f32x4 acc = {0.f, 0.f, 0.f, 0.f};
            acc = __builtin_amdgcn_mfma_f32_16x16x32_bf16(Ah0, Bh0, acc, 0, 0, 0);
            acc = __builtin_amdgcn_mfma_f32_16x16x32_bf16(Ah1, Bh1, acc, 0, 0, 0);
            acc = __builtin_amdgcn_mfma_f32_16x16x32_bf16(Ah0, Bl0, acc, 0, 0, 0);
            acc = __builtin_amdgcn_mfma_f32_16x16x32_bf16(Ah1, Bl1, acc, 0, 0, 0);
            acc = __builtin_amdgcn_mfma_f32_16x16x32_bf16(Al0, Bh0, acc, 0, 0, 0);
            acc = __builtin_amdgcn_mfma_f32_16x16x32_bf16(Al1, Bh1, acc, 0, 0, 0);
            float cminv = INFINITY;
            #pragma unroll
            for (int r = 0; r < 4; r++) {
                float wv = fmaf(acc[r], -2.0f, cn4v);            // 4 + cn - 2s  (>0)
                unsigned kk = (__float_as_uint(wv) & 0xFFFFFC00u) | kid;
                unsigned mx = m1[r] > kk ? m1[r] : kk;
                m2[r] = m2[r] < mx ? m2[r] : mx;
                m1[r] = m1[r] < kk ? m1[r] : kk;
                cminv = fminf(cminv, wv + xnm4[r]);              // full dist (entropy)
            }
            cminv = fminf(cminv, __shfl_xor(cminv, 16));
            cminv = fminf(cminv, __shfl_xor(cminv, 32));
            if (q == ct) scrE[wi*1024 + cc*64 + lane] = cminv;   // lane == ct*16+ln15
        }
        if (cc < 15) {
            #pragma unroll
            for (int i = 0; i < 4; i++) *(float4*)(Bb[(cc+1)&1] + (i*256 + tid)*16) = st[i];
        }
    }
    __syncthreads();   // scrE complete

    // ---- butterfly top-2 merge across the 16 code-column lanes (fixed q) ----
    #pragma unroll
    for (int d = 1; d < 16; d <<= 1) {
        #pragma unroll
        for (int r = 0; r < 4; r++) {
            unsigned o1 = (unsigned)__shfl_xor((int)m1[r], d);
            unsigned o2 = (unsigned)__shfl_xor((int)m2[r], d);
            unsigned mx  = m1[r] > o1 ? m1[r] : o1;
            unsigned mn2 = m2[r] < o2 ? m2[r] : o2;
            m2[r] = mn2 < mx ? mn2 : mx;
            m1[r] = m1[r] < o1 ? m1[r] : o1;
        }
    }
    if (ln15 == 0) {
        #pragma unroll
        for (int r = 0; r < 4; r++) {
            int tok = (int)(m1[r] & 1023u);
            tokS[wi*16 + q*4 + r] = tok;
            float g1 = __uint_as_float(m1[r] & 0xFFFFFC00u);
            float g2 = __uint_as_float(m2[r] & 0xFFFFFC00u);
            if (g2 - g1 < GAP_THRESH) {
                unsigned idx = atomicAdd(counter, 1u);
                if (idx < AMB_CAP) {
                    amb[2*idx]   = row0 + wi*16 + q*4 + r;
                    amb[2*idx+1] = tok;
                }
            }
        }
    }
    __syncthreads();   // tokS ready

    // ---- entropy: combine 4 waves, write per-block row (coalesced) ----
    #pragma unroll
    for (int jj = 0; jj < 4; jj++) {
        int c = jj*256 + tid;
        float e = fminf(fminf(scrE[c], scrE[1024 + c]),
                        fminf(scrE[2048 + c], scrE[3072 + c]));
        entPartial[(size_t)blockIdx.x * 1024 + c] = e;
    }

    // ---- emb gather + sumsq (256 threads over 64 rows x 4 parts) ----
    {
        int grow = tid >> 2, p = tid & 3;
        int tok = tokS[grow];
        const float4* cv = (const float4*)(cb + (size_t)tok*64 + p*16);
        const float4* xv = (const float4*)(x  + (size_t)(row0 + grow)*64 + p*16);
        float4* ov = (float4*)(out + (size_t)(row0 + grow)*64 + p*16);
        float acc2 = 0.f;
        #pragma unroll
        for (int i = 0; i < 4; i++) {
            float4 c = cv[i]; float4 xx = xv[i];
            ov[i] = c;
            float dx = c.x-xx.x, dy = c.y-xx.y, dz = c.z-xx.z, dw = c.w-xx.w;
            acc2 += dx*dx + dy*dy + dz*dz + dw*dw;
        }
        #pragma unroll
        for (int o = 32; o > 0; o >>= 1) acc2 += __shfl_down(acc2, o);
        if ((tid & 63) == 0) redS[tid >> 6] = acc2;
        __syncthreads();
        if (tid == 0) atomicAdd(gsumsq, redS[0] + redS[1] + redS[2] + redS[3]);
    }
}

// ---------------------------------------------------------------------------
// ent: minDist[k] = min over 512 blocks of entPartial[b][k]. Grid 64 x 256.
// ---------------------------------------------------------------------------
__global__ __launch_bounds__(256) void vq_ent(
    const float* __restrict__ entPartial, float* __restrict__ minDist)
{
    __shared__ float red[256];
    int tid = threadIdx.x;
    int cof = tid & 15, sl = tid >> 4;      // 16 codes x 16 block-slices
    int code = blockIdx.x * 16 + cof;
    const float* p = entPartial + (size_t)(sl * 32) * 1024 + code;
    float m = INFINITY;
    #pragma unroll 8
    for (int i = 0; i < 32; i++) m = fminf(m, p[(size_t)i * 1024]);
    red[tid] = m;
    __syncthreads();
    #pragma unroll
    for (int h = 8; h > 0; h >>= 1) {
        if (sl < h) red[tid] = fminf(red[tid], red[tid + h*16]);
        __syncthreads();
    }
    if (tid < 16) minDist[blockIdx.x * 16 + tid] = red[tid];
}

// ---------------------------------------------------------------------------
// fixup: block-per-ambiguous-row full fp64 argmin, float4-vectorized cb reads
// ---------------------------------------------------------------------------
__global__ __launch_bounds__(256) void vq_fixup(
    const float* __restrict__ x, const float* __restrict__ cb,
    float* __restrict__ out, const unsigned* __restrict__ counter,
    const int* __restrict__ amb, float* __restrict__ gsumsq)
{
    __shared__ double xs[64];
    __shared__ double bd[256];
    __shared__ int    bi[256];
    int tid = threadIdx.x;
    unsigned cnt = *counter; if (cnt > AMB_CAP) cnt = AMB_CAP;
    for (unsigned i = blockIdx.x; i < cnt; i += gridDim.x) {
        int row = amb[2*i], oldk = amb[2*i+1];
        __syncthreads();
        if (tid < 64) xs[tid] = (double)x[(size_t)row*64 + tid];
        __syncthreads();
        double xn = 0.0;
        #pragma unroll 8
        for (int d = 0; d < 64; d++) xn += xs[d]*xs[d];
        double best = INFINITY; int bk = 1 << 30;
        #pragma unroll
        for (int j = 0; j < 4; j++) {
            int k = j*256 + tid;
            const float4* c4 = (const float4*)(cb + (size_t)k*64);
            double dot = 0.0, cn2 = 0.0;
            #pragma unroll
            for (int t = 0; t < 16; t++) {
                float4 cv = c4[t];
                double cx = (double)cv.x, cy = (double)cv.y, cz = (double)cv.z, cw = (double)cv.w;
                dot += xs[t*4+0]*cx + xs[t*4+1]*cy + xs[t*4+2]*cz + xs[t*4+3]*cw;
                cn2 += cx*cx + cy*cy + cz*cz + cw*cw;
            }
            double dist = (xn - 2.0*dot) + cn2;
            if (dist < best || (dist == best && k < bk)) { best = dist; bk = k; }
        }
        bd[tid] = best; bi[tid] = bk;
        __syncthreads();
        for (int s = 128; s > 0; s >>= 1) {
            if (tid < s) {
                double od = bd[tid+s]; int ok = bi[tid+s];
                if (od < bd[tid] || (od == bd[tid] && ok < bi[tid])) { bd[tid] = od; bi[tid] = ok; }
            }
            __syncthreads();
        }
        int bestk = bi[0];
        if (bestk != oldk) {
            double part = 0.0;
            if (tid < 64) {
                float cn = cb[(size_t)bestk*64 + tid];
                float co = cb[(size_t)oldk*64 + tid];
                out[(size_t)row*64 + tid] = cn;
                double dn = (double)cn - xs[tid];
                double dl = (double)co - xs[tid];
                part = dn*dn - dl*dl;
            }
            __syncthreads();
            bd[tid] = part;
            __syncthreads();
            for (int s = 128; s > 0; s >>= 1) {
                if (tid < s) bd[tid] += bd[tid+s];
                __syncthreads();
            }
            if (tid == 0) atomicAdd(gsumsq, (float)bd[0]);
        }
    }
}

// ---------------------------------------------------------------------------
// finalize: loss = 1.25*sumsq/2097152 + 0.1*mean(minDist)
// ---------------------------------------------------------------------------
__global__ __launch_bounds__(256) void vq_finalize(
    const float* __restrict__ minDist, const float* __restrict__ gsumsq,
    float* __restrict__ out_loss)
{
    __shared__ float redS[4];
    float s = 0.f;
    for (int k = threadIdx.x; k < NCODE; k += 256) s += minDist[k];
    #pragma unroll
    for (int o = 32; o > 0; o >>= 1) s += __shfl_down(s, o);
    if ((threadIdx.x & 63) == 0) redS[threadIdx.x >> 6] = s;
    __syncthreads();
    if (threadIdx.x == 0) {
        float tot = redS[0] + redS[1] + redS[2] + redS[3];
        out_loss[0] = 1.25f * (*gsumsq / 2097152.0f) + 0.1f * (tot / 1024.0f);
    }
}

extern "C" void kernel_launch(void* const* d_in, const int* in_sizes, int n_in,
                              void* d_out, int out_size, void* d_ws, size_t ws_size,
                              hipStream_t stream) {
    const float* x  = (const float*)d_in[0];   // [32768, 64]
    const float* cb = (const float*)d_in[1];   // [1024, 64]
    float* out = (float*)d_out;                // [0,2097152): emb; [2097152]: loss

    char* ws = (char*)d_ws;
    unsigned*       counter    = (unsigned*)ws;                    // @0
    float*          gsumsq     = (float*)(ws + 4);                 // @4
    float*          cn4        = (float*)(ws + 1024);              // 4 KB
    int*            amb        = (int*)(ws + 16384);               // 64 KB
    unsigned short* wsB        = (unsigned short*)(ws + 131072);   // 256 KB
    float*          minDist    = (float*)(ws + 393216);            // 4 KB
    float*          entPartial = (float*)(ws + 524288);            // 2 MB

    vq_prep    <<<4,   256, 0, stream>>>(cb, cn4, counter, gsumsq, wsB);
    vq_main    <<<512, 256, 0, stream>>>(x, cb, wsB, cn4, out, entPartial, counter, amb, gsumsq);
    vq_ent     <<<64,  256, 0, stream>>>(entPartial, minDist);
    vq_fixup   <<<256, 256, 0, stream>>>(x, cb, out, counter, amb, gsumsq);
    vq_finalize<<<1,   256, 0, stream>>>(minDist, gsumsq, out + 2097152);
}

// Round 4
// 138.941 us; speedup vs baseline: 1.3951x; 1.1314x over previous
//
#include <hip/hip_runtime.h>
#include <math.h>

#define NROWS 32768
#define NCODE 1024
#define AMB_CAP 8192
#define GAP_THRESH 1.5e-4f  // exact fp32 gap; emulation err ~1e-5, np-ref rounding ~2e-5

typedef __attribute__((ext_vector_type(8))) short bf16x8;   // 8 bf16 = 4 VGPRs
typedef __attribute__((ext_vector_type(4))) float f32x4;    // MFMA acc

__device__ __forceinline__ unsigned short bf16_rne(float f) {
    unsigned u = __float_as_uint(f);
    unsigned r = u + 0x7FFFu + ((u >> 16) & 1u);
    return (unsigned short)(r >> 16);
}

typedef const __attribute__((address_space(1))) unsigned GU;
typedef __attribute__((address_space(3))) unsigned LU;
__device__ __forceinline__ void gl_lds16(const void* g, void* l) {
    __builtin_amdgcn_global_load_lds((GU*)g, (LU*)l, 16, 0, 0);
}
__device__ __forceinline__ void gl_lds4(const void* g, void* l) {
    __builtin_amdgcn_global_load_lds((GU*)g, (LU*)l, 4, 0, 0);
}

// ---------------------------------------------------------------------------
// prep: cn4 = ||c||^2+4, zero counter/gsumsq/ticket, codebook -> frag-major
// split-bf16 (wsB). chunk cc=c>>6 (16KB) | tile ct=(c>>4)&3 (4KB) | frag q
// {hi0-31,hi32-63,lo0-31,lo32-63} (1KB) | lane (g*16+c&15)*16B.
// ---------------------------------------------------------------------------
__global__ __launch_bounds__(256) void vq_prep(
    const float* __restrict__ cb, float* __restrict__ cn4,
    unsigned* __restrict__ counter, float* __restrict__ gsumsq,
    unsigned* __restrict__ ticket, unsigned short* __restrict__ wsB)
{
    int c = blockIdx.x * 256 + threadIdx.x;
    if (c == 0) { *counter = 0u; *gsumsq = 0.f; *ticket = 0u; }
    if (c >= NCODE) return;
    float v[64];
    const float4* src = (const float4*)(cb + (size_t)c * 64);
    float s = 0.f;
    #pragma unroll
    for (int i = 0; i < 16; i++) {
        float4 t = src[i];
        v[i*4+0] = t.x; v[i*4+1] = t.y; v[i*4+2] = t.z; v[i*4+3] = t.w;
        s += t.x*t.x + t.y*t.y + t.z*t.z + t.w*t.w;
    }
    cn4[c] = s + 4.0f;
    int cc = c >> 6, ct = (c >> 4) & 3, cl = c & 15;
    #pragma unroll
    for (int q = 0; q < 4; q++) {
        int half = q & 1, lo = q >> 1;
        #pragma unroll
        for (int g = 0; g < 4; g++) {
            unsigned short u8[8] __attribute__((aligned(16)));
            #pragma unroll
            for (int j = 0; j < 8; j++) {
                float f = v[half*32 + g*8 + j];
                unsigned short h = bf16_rne(f);
                if (lo) h = bf16_rne(f - __uint_as_float((unsigned)h << 16));
                u8[j] = h;
            }
            size_t off = (size_t)cc * 8192 + ct * 2048 + q * 512 + (g * 16 + cl) * 8;
            *(uint4*)(wsB + off) = *(const uint4*)u8;
        }
    }
}

// ---------------------------------------------------------------------------
// main: block = 64 rows x ALL 1024 codes; 4 waves x 16 rows. B double-buffered
// via global_load_lds(16B); cn4 staged via global_load_lds(4B) (separate from
// the ds counter, so no vmcnt cross-drain on cn4 use). Exact (d1,i1,d2) top-2
// in regs; entropy via LDS atomicMin on raw f32 bits (dist>0). Emb fused.
// ---------------------------------------------------------------------------
__global__ __launch_bounds__(256, 4) void vq_main(
    const float* __restrict__ x, const float* __restrict__ cb,
    const unsigned short* __restrict__ wsB, const float* __restrict__ cn4,
    float* __restrict__ out, float* __restrict__ entPartial,
    unsigned* __restrict__ counter, int* __restrict__ amb,
    float* __restrict__ gsumsq)
{
    __shared__ __align__(16) unsigned char Bb[2][16384];
    __shared__ float cn4L[2][64];
    __shared__ unsigned scrE[1024];   // per-block per-code min dist (raw f32 bits)
    __shared__ int   tokS[64];
    __shared__ float redS[4];

    const int tid = threadIdx.x;
    const int lane = tid & 63;
    const int wi = tid >> 6;
    const int ln15 = lane & 15;
    const int q = lane >> 4;
    const int row0 = blockIdx.x * 64;
    const int wrow = row0 + wi * 16;

    // init scrE to +inf bits
    #pragma unroll
    for (int jj = 0; jj < 4; jj++) scrE[jj*256 + tid] = 0x7F800000u;

    // preload chunk 0 (B + cn4) straight into LDS
    const char* wsBb = (const char*)wsB;
    {
        int wbase = (tid & ~63) * 16;   // wave-uniform part of (i*256+tid)*16
        #pragma unroll
        for (int i = 0; i < 4; i++)
            gl_lds16(wsBb + (i*256 + tid)*16, (void*)&Bb[0][i*4096 + wbase]);
        if (wi == 0) gl_lds4(cn4 + lane, (void*)&cn4L[0][0]);
    }

    // ---- A: 16 rows fp32 -> split-bf16 frags in regs; row norms via shfl ----
    bf16x8 Ah0, Ah1, Al0, Al1;
    float xnm4[4];
    {
        const float* xr = x + (size_t)(wrow + ln15) * 64 + q * 8;
        float4 f0 = *(const float4*)xr;
        float4 f1 = *(const float4*)(xr + 4);
        float4 f2 = *(const float4*)(xr + 32);
        float4 f3 = *(const float4*)(xr + 36);
        float fa[8] = {f0.x,f0.y,f0.z,f0.w,f1.x,f1.y,f1.z,f1.w};
        float fb[8] = {f2.x,f2.y,f2.z,f2.w,f3.x,f3.y,f3.z,f3.w};
        unsigned short h[8]  __attribute__((aligned(16)));
        unsigned short l[8]  __attribute__((aligned(16)));
        unsigned short h2[8] __attribute__((aligned(16)));
        unsigned short l2[8] __attribute__((aligned(16)));
        float ss = 0.f;
        #pragma unroll
        for (int j = 0; j < 8; j++) {
            ss += fa[j]*fa[j] + fb[j]*fb[j];
            unsigned short hh = bf16_rne(fa[j]);
            h[j] = hh; l[j] = bf16_rne(fa[j] - __uint_as_float((unsigned)hh << 16));
            hh = bf16_rne(fb[j]);
            h2[j] = hh; l2[j] = bf16_rne(fb[j] - __uint_as_float((unsigned)hh << 16));
        }
        Ah0 = *(const bf16x8*)h;  Al0 = *(const bf16x8*)l;
        Ah1 = *(const bf16x8*)h2; Al1 = *(const bf16x8*)l2;
        ss += __shfl_xor(ss, 16);
        ss += __shfl_xor(ss, 32);            // ||x_row(ln15)||^2
        #pragma unroll
        for (int r = 0; r < 4; r++)
            xnm4[r] = __shfl(ss, (q << 2) | r, 64) - 4.0f;  // xn(row q*4+r) - 4
    }

    float d1[4], d2[4];
    int   i1[4];
    #pragma unroll
    for (int r = 0; r < 4; r++) { d1[r] = INFINITY; d2[r] = INFINITY; i1[r] = 0; }

    // ---- chunk loop over all 1024 codes ----
    for (int cc = 0; cc < 16; cc++) {
        __syncthreads();   // drains prefetch: buf[cc&1]+cn4L[cc&1] ready; buf[nb] free
        const int cb_ = cc & 1, nb = (cc + 1) & 1;
        if (cc < 15) {
            int wbase = (tid & ~63) * 16;
            #pragma unroll
            for (int i = 0; i < 4; i++)
                gl_lds16(wsBb + (cc+1)*16384 + (i*256 + tid)*16,
                         (void*)&Bb[nb][i*4096 + wbase]);
            if (wi == 0) gl_lds4(cn4 + (cc+1)*64 + lane, (void*)&cn4L[nb][0]);
        }
        const unsigned char* buf = Bb[cb_];
        #pragma unroll
        for (int ct = 0; ct < 4; ct++) {
            bf16x8 Bh0 = *(const bf16x8*)(buf + ct*4096 +    0 + lane*16);
            bf16x8 Bh1 = *(const bf16x8*)(buf + ct*4096 + 1024 + lane*16);
            bf16x8 Bl0 = *(const bf16x8*)(buf + ct*4096 + 2048 + lane*16);
            bf16x8 Bl1 = *(const bf16x8*)(buf + ct*4096 + 3072 + lane*16);
            float cn4v = cn4L[cb_][ct*16 + ln15];
            int kid = cc*64 + ct*16 + ln15;
            f32x4 acc = {0.f, 0.f, 0.f, 0.f};
            acc = __builtin_amdgcn_mfma_f32_16x16x32_bf16(Ah0, Bh0, acc, 0, 0, 0);
            acc = __builtin_amdgcn_mfma_f32_16x16x32_bf16(Ah1, Bh1, acc, 0, 0, 0);
            acc = __builtin_amdgcn_mfma_f32_16x16x32_bf16(Ah0, Bl0, acc, 0, 0, 0);
            acc = __builtin_amdgcn_mfma_f32_16x16x32_bf16(Ah1, Bl1, acc, 0, 0, 0);
            acc = __builtin_amdgcn_mfma_f32_16x16x32_bf16(Al0, Bh0, acc, 0, 0, 0);
            acc = __builtin_amdgcn_mfma_f32_16x16x32_bf16(Al1, Bh1, acc, 0, 0, 0);
            float cminv = INFINITY;
            #pragma unroll
            for (int r = 0; r < 4; r++) {
                float wv = fmaf(acc[r], -2.0f, cn4v);   // 4 + cn - 2s  (>0)
                bool lt = wv < d1[r];
                d2[r] = lt ? d1[r] : fminf(d2[r], wv);
                i1[r] = lt ? kid   : i1[r];
                d1[r] = lt ? wv    : d1[r];
                cminv = fminf(cminv, wv + xnm4[r]);     // full dist (entropy)
            }
            cminv = fminf(cminv, __shfl_xor(cminv, 16));
            cminv = fminf(cminv, __shfl_xor(cminv, 32));
            if (q == ct) atomicMin(&scrE[kid], __float_as_uint(cminv));
        }
    }
    __syncthreads();   // scrE complete

    // ---- butterfly exact top-2 merge across the 16 code-column lanes ----
    #pragma unroll
    for (int d = 1; d < 16; d <<= 1) {
        #pragma unroll
        for (int r = 0; r < 4; r++) {
            float od1 = __shfl_xor(d1[r], d);
            int   oi1 = __shfl_xor(i1[r], d);
            float od2 = __shfl_xor(d2[r], d);
            bool take = (od1 < d1[r]) || (od1 == d1[r] && oi1 < i1[r]);
            float loser = take ? d1[r] : od1;
            d2[r] = fminf(fminf(d2[r], od2), loser);
            d1[r] = take ? od1 : d1[r];
            i1[r] = take ? oi1 : i1[r];
        }
    }
    if (ln15 == 0) {
        #pragma unroll
        for (int r = 0; r < 4; r++) {
            tokS[wi*16 + q*4 + r] = i1[r];
            if (d2[r] - d1[r] < GAP_THRESH) {
                unsigned idx = atomicAdd(counter, 1u);
                if (idx < AMB_CAP) {
                    amb[2*idx]   = row0 + wi*16 + q*4 + r;
                    amb[2*idx+1] = i1[r];
                }
            }
        }
    }
    __syncthreads();   // tokS ready

    // ---- entropy partials: coalesced per-block row ----
    #pragma unroll
    for (int jj = 0; jj < 4; jj++) {
        int c = jj*256 + tid;
        entPartial[(size_t)blockIdx.x * 1024 + c] = __uint_as_float(scrE[c]);
    }

    // ---- emb gather + sumsq ----
    {
        int grow = tid >> 2, p = tid & 3;
        int tok = tokS[grow];
        const float4* cv = (const float4*)(cb + (size_t)tok*64 + p*16);
        const float4* xv = (const float4*)(x  + (size_t)(row0 + grow)*64 + p*16);
        float4* ov = (float4*)(out + (size_t)(row0 + grow)*64 + p*16);
        float acc2 = 0.f;
        #pragma unroll
        for (int i = 0; i < 4; i++) {
            float4 c = cv[i]; float4 xx = xv[i];
            ov[i] = c;
            float dx = c.x-xx.x, dy = c.y-xx.y, dz = c.z-xx.z, dw = c.w-xx.w;
            acc2 += dx*dx + dy*dy + dz*dz + dw*dw;
        }
        #pragma unroll
        for (int o = 32; o > 0; o >>= 1) acc2 += __shfl_down(acc2, o);
        if ((tid & 63) == 0) redS[tid >> 6] = acc2;
        __syncthreads();
        if (tid == 0) atomicAdd(gsumsq, redS[0] + redS[1] + redS[2] + redS[3]);
    }
}

// ---------------------------------------------------------------------------
// tail: (A) minDist columns from entPartial; (B) fp64 fixup of ambiguous rows;
// (C) last-block-done writes the loss. 256 blocks x 256 threads.
// ---------------------------------------------------------------------------
__global__ __launch_bounds__(256) void vq_tail(
    const float* __restrict__ x, const float* __restrict__ cb,
    float* __restrict__ out, const float* __restrict__ entPartial,
    const unsigned* __restrict__ counter, const int* __restrict__ amb,
    float* __restrict__ gsumsq, unsigned* __restrict__ ticket,
    float* __restrict__ minDist, float* __restrict__ out_loss)
{
    __shared__ double xs[64];
    __shared__ double bd[256];
    __shared__ int    bi[256];
    __shared__ unsigned lastS;
    __shared__ float redS[4];

    const int tid = threadIdx.x;
    const int lane = tid & 63;

    // ---- A: per-code min over the 512 block-partials ----
    {
        int code = blockIdx.x * 4 + (tid >> 6);
        const float* p = entPartial + (size_t)lane * 1024 + code;
        float m = INFINITY;
        #pragma unroll
        for (int j = 0; j < 8; j++) m = fminf(m, p[(size_t)j * 64 * 1024]);
        #pragma unroll
        for (int o = 32; o > 0; o >>= 1) m = fminf(m, __shfl_down(m, o));
        if (lane == 0) minDist[code] = m;
    }

    // ---- B: fp64 re-decision for ambiguous rows ----
    unsigned cnt = *counter; if (cnt > AMB_CAP) cnt = AMB_CAP;
    for (unsigned i = blockIdx.x; i < cnt; i += gridDim.x) {
        int row = amb[2*i], oldk = amb[2*i+1];
        __syncthreads();
        if (tid < 64) xs[tid] = (double)x[(size_t)row*64 + tid];
        __syncthreads();
        double xn = 0.0;
        #pragma unroll 8
        for (int d = 0; d < 64; d++) xn += xs[d]*xs[d];
        double best = INFINITY; int bk = 1 << 30;
        #pragma unroll
        for (int j = 0; j < 4; j++) {
            int k = j*256 + tid;
            const float4* c4 = (const float4*)(cb + (size_t)k*64);
            double dot = 0.0, cn2 = 0.0;
            #pragma unroll
            for (int t = 0; t < 16; t++) {
                float4 cv = c4[t];
                double cx = (double)cv.x, cy = (double)cv.y, cz = (double)cv.z, cw = (double)cv.w;
                dot += xs[t*4+0]*cx + xs[t*4+1]*cy + xs[t*4+2]*cz + xs[t*4+3]*cw;
                cn2 += cx*cx + cy*cy + cz*cz + cw*cw;
            }
            double dist = (xn - 2.0*dot) + cn2;
            if (dist < best || (dist == best && k < bk)) { best = dist; bk = k; }
        }
        bd[tid] = best; bi[tid] = bk;
        __syncthreads();
        for (int s = 128; s > 0; s >>= 1) {
            if (tid < s) {
                double od = bd[tid+s]; int ok = bi[tid+s];
                if (od < bd[tid] || (od == bd[tid] && ok < bi[tid])) { bd[tid] = od; bi[tid] = ok; }
            }
            __syncthreads();
        }
        int bestk = bi[0];
        if (bestk != oldk) {
            double part = 0.0;
            if (tid < 64) {
                float cn = cb[(size_t)bestk*64 + tid];
                float co = cb[(size_t)oldk*64 + tid];
                out[(size_t)row*64 + tid] = cn;
                double dn = (double)cn - xs[tid];
                double dl = (double)co - xs[tid];
                part = dn*dn - dl*dl;
            }
            __syncthreads();
            bd[tid] = part;
            __syncthreads();
            for (int s = 128; s > 0; s >>= 1) {
                if (tid < s) bd[tid] += bd[tid+s];
                __syncthreads();
            }
            if (tid == 0) atomicAdd(gsumsq, (float)bd[0]);
        }
    }

    // ---- C: last block assembles the loss ----
    __syncthreads();
    if (tid == 0) {
        __threadfence();
        lastS = (atomicAdd(ticket, 1u) == (unsigned)(gridDim.x - 1)) ? 1u : 0u;
    }
    __syncthreads();
    if (lastS) {
        __threadfence();
        volatile const float* md = minDist;
        float s = 0.f;
        #pragma unroll
        for (int jj = 0; jj < 4; jj++) s += md[jj*256 + tid];
        #pragma unroll
        for (int o = 32; o > 0; o >>= 1) s += __shfl_down(s, o);
        if ((tid & 63) == 0) redS[tid >> 6] = s;
        __syncthreads();
        if (tid == 0) {
            volatile const float* gs = gsumsq;
            float tot = redS[0] + redS[1] + redS[2] + redS[3];
            out_loss[0] = 1.25f * (*gs / 2097152.0f) + 0.1f * (tot / 1024.0f);
        }
    }
}

extern "C" void kernel_launch(void* const* d_in, const int* in_sizes, int n_in,
                              void* d_out, int out_size, void* d_ws, size_t ws_size,
                              hipStream_t stream) {
    const float* x  = (const float*)d_in[0];   // [32768, 64]
    const float* cb = (const float*)d_in[1];   // [1024, 64]
    float* out = (float*)d_out;                // [0,2097152): emb; [2097152]: loss

    char* ws = (char*)d_ws;
    unsigned*       counter    = (unsigned*)ws;                    // @0
    float*          gsumsq     = (float*)(ws + 4);                 // @4
    unsigned*       ticket     = (unsigned*)(ws + 8);              // @8
    float*          cn4        = (float*)(ws + 1024);              // 4 KB
    int*            amb        = (int*)(ws + 16384);               // 64 KB
    unsigned short* wsB        = (unsigned short*)(ws + 131072);   // 256 KB
    float*          minDist    = (float*)(ws + 393216);            // 4 KB
    float*          entPartial = (float*)(ws + 524288);            // 2 MB

    vq_prep<<<4,   256, 0, stream>>>(cb, cn4, counter, gsumsq, ticket, wsB);
    vq_main<<<512, 256, 0, stream>>>(x, cb, wsB, cn4, out, entPartial, counter, amb, gsumsq);
    vq_tail<<<256, 256, 0, stream>>>(x, cb, out, entPartial, counter, amb, gsumsq, ticket,
                                     minDist, out + 2097152);
}